// Round 13
// baseline (450.241 us; speedup 1.0000x reference)
//
#include <hip/hip_runtime.h>
#include <stdint.h>

// GraphSAGE MI355X — round 11: fused cone kernel, h2 streamed via global_load_lds
// (2-phase double-buffered pipeline, catalog T3-minimum). Tests whether
// direct-to-LDS DMA lifts streaming-read BW past the ~4.5 TB/s VGPR-return cap.
// Block b owns output rows 2b,2b+1. Cone: h1[20b..20b+19], h0[2b..2b+1],
// h2[200b..200b+199].
//   stage(0); phase0a (self rows -> lA cols-half, pads zero); sync (drains vm);
//   phase0b (hop-0 means from cache-hot h1) ;
//   pipeline c=0..9: { stage(c+1); consume(c): mean10 raw->lA mean rows 2c,2c+1; sync }
//   layer1 MFMA (lA[32][512] @ W1t^T) -> relu -> lNH[32][256] (overlay in raw)
//   sync; phase2: lA2[16][512] = [nh0 | mean10(nh1)]; sync; layer2 -> out.
// LDS: raw 2x20K + lA 32K = 72KB dynamic -> 2 blocks/CU; lNH/lA2 overlay raw.

typedef unsigned short u16;
typedef __attribute__((ext_vector_type(2))) float f32x2;
typedef __attribute__((ext_vector_type(4))) float f32x4;
typedef __attribute__((ext_vector_type(8))) short s16x8;
typedef __attribute__((ext_vector_type(4))) unsigned short u16x4;

__device__ inline u16 f2bf(float x) {
    union { float f; uint32_t u; } v; v.f = x;
    uint32_t b = v.u;
    b += 0x7FFFu + ((b >> 16) & 1u);   // round-to-nearest-even
    return (u16)(b >> 16);
}
__device__ inline float bf2f(u16 u) {
    union { uint32_t u; float f; } v; v.u = ((uint32_t)u) << 16;
    return v.f;
}

// Transposed bf16 weight build: dst[n][koff+k] = f2bf(src[k][n]), 64x64 tiles.
__global__ __launch_bounds__(256) void conv_w2t(const float* __restrict__ w1s,
                                                const float* __restrict__ w1n,
                                                const float* __restrict__ w2s,
                                                const float* __restrict__ w2n,
                                                u16* __restrict__ W1t,
                                                u16* __restrict__ W2t) {
    __shared__ u16 t[64][66];
    const int b = blockIdx.x;
    const int mat = b >> 4;
    const int tk = ((b >> 2) & 3) * 64;
    const int tn = (b & 3) * 64;
    const float* src = (mat == 0) ? w1s : (mat == 1) ? w1n : (mat == 2) ? w2s : w2n;
    u16* dst = (mat < 2) ? W1t : W2t;
    const int koff = (mat & 1) * 256;
    const int tid = threadIdx.x;
    const int li = tid >> 6, ln = tid & 63;
    #pragma unroll
    for (int p = 0; p < 16; ++p) {
        int k = p * 4 + li;
        t[k][ln] = f2bf(src[(size_t)(tk + k) * 256 + tn + ln]);
    }
    __syncthreads();
    #pragma unroll
    for (int p = 0; p < 16; ++p) {
        int n = p * 4 + li;
        dst[(size_t)(tn + n) * 512 + koff + tk + ln] = t[ln][n];
    }
}

// ---- swizzled LDS tile helpers (phys chunk = logical chunk ^ (row&7)) ------
__device__ inline void storeA(u16* t, int r, int c, u16x4 v) {      // row=512 u16
    int byte = c * 2, chunk = byte >> 4, off = byte & 15;
    *(u16x4*)((char*)(t + (size_t)r * 512) + ((chunk ^ (r & 7)) * 16) + off) = v;
}
__device__ inline void storeA4(u16* t, int r, int c, uint32_t v) {  // 4B, c mult 2
    int byte = c * 2, chunk = byte >> 4, off = byte & 15;
    *(uint32_t*)((char*)(t + (size_t)r * 512) + ((chunk ^ (r & 7)) * 16) + off) = v;
}
__device__ inline s16x8 readA8(const u16* t, int r, int k) {        // 16B, k mult 8
    int chunk = (k * 2) >> 4;
    return *(const s16x8*)((const char*)(t + (size_t)r * 512) + ((chunk ^ (r & 7)) * 16));
}
__device__ inline void storeNH1(u16* t, int r, int c, u16 v) {      // row=256 u16
    int byte = c * 2, chunk = byte >> 4, off = byte & 15;
    *(u16*)((char*)(t + (size_t)r * 256) + ((chunk ^ (r & 7)) * 16) + off) = v;
}
__device__ inline u16x4 readNH4(const u16* t, int r, int c) {       // 8B, c mult 4
    int byte = c * 2, chunk = byte >> 4, off = byte & 15;
    return *(const u16x4*)((const char*)(t + (size_t)r * 256) + ((chunk ^ (r & 7)) * 16) + off);
}

__device__ inline void gl16(const void* g, void* l) {
    __builtin_amdgcn_global_load_lds((const __attribute__((address_space(1))) void*)g,
                                     (__attribute__((address_space(3))) void*)l, 16, 0, 0);
}

// LDS byte map (dynamic, 73728 B total):
//   raw[0] [0,20480)   raw[1] [20480,40960)   (20 h2 rows x 1KB each)
//   lA     [40960,73728)  = [32][512] bf16 swizzled
// overlays after raw is dead:
//   lNH [0,16384) = [32][256] bf16 ;  lA2 [16384,32768) = [16][512] bf16
#define RAW_OFF(i)  ((i) * 20480)
#define LA_OFF      40960
#define LNH_OFF     0
#define LA2_OFF     16384
#define K1_LDS      73728

__global__ __launch_bounds__(256, 2) void sage_fused(const float* __restrict__ h0,
                                                     const float* __restrict__ h1,
                                                     const float* __restrict__ h2,
                                                     const u16* __restrict__ W1t,
                                                     const u16* __restrict__ W2t,
                                                     float* __restrict__ out) {
    extern __shared__ __align__(16) char smem[];
    u16* lA  = (u16*)(smem + LA_OFF);
    u16* lNH = (u16*)(smem + LNH_OFF);
    u16* lA2 = (u16*)(smem + LA2_OFF);

    const int b = blockIdx.x;
    const int tid = threadIdx.x;
    const int lane = tid & 63;
    const int w = tid >> 6;
    const int an = lane & 15;
    const int ak = (lane >> 4) * 8;

    // stage h2 chunk c (20 rows x 1KB) into raw[c&1]; 5 gl_lds per wave
    auto stage = [&](int c) {
        char* rb = smem + RAW_OFF(c & 1);
        #pragma unroll
        for (int k = 0; k < 5; ++k) {
            int i = w * 5 + k;                       // 0..19
            const float* g = h2 + (size_t)(200 * b + 20 * c + i) * 256 + lane * 4;
            gl16(g, rb + i * 1024);
        }
    };

    stage(0);                                        // flies during phase0a

    // ---- phase 0a: self cols-half (rows 0-19 h1, 20-21 h0), pads zero
    #pragma unroll
    for (int p = 0; p < 8; ++p) {
        int task = p * 256 + tid;                    // 32 rows x 64 quads
        int r = task >> 6;
        int c4 = (task & 63) * 4;
        u16x4 sb = {0, 0, 0, 0};
        if (r < 22) {
            const float* sp = (r < 20) ? h1 + (size_t)(20 * b + r) * 256
                                       : h0 + (size_t)(2 * b + (r - 20)) * 256;
            f32x4 v = *(const f32x4*)(sp + c4);
            #pragma unroll
            for (int i = 0; i < 4; ++i) sb[i] = f2bf(v[i]);
        }
        storeA(lA, r, c4, sb);
        if (r >= 22) storeA(lA, r, 256 + c4, sb);    // zero mean-half of pads
    }
    __syncthreads();   // drains vmcnt: raw[0] landed, h1 lines L2-hot

    // ---- phase 0b: hop-0 neighbor means from cache-hot h1 (f32, same order as R10)
    {
        int orow = tid >> 7;                         // 0..1
        int cp = tid & 127;                          // f32x2 column pair
        const float* base = h1 + (size_t)(20 * b + orow * 10) * 256 + cp * 2;
        f32x2 s = {0.f, 0.f};
        #pragma unroll
        for (int j = 0; j < 10; ++j)
            s += *(const f32x2*)(base + (size_t)j * 256);
        uint32_t pk = (uint32_t)f2bf(s[0] * 0.1f) | ((uint32_t)f2bf(s[1] * 0.1f) << 16);
        storeA4(lA, 20 + orow, 256 + cp * 2, pk);
    }

    // ---- pipeline: 10 chunks, 2-phase (stage next || consume current)
    for (int c = 0; c < 10; ++c) {
        if (c < 9) stage(c + 1);
        {   // consume raw[c&1]: mean10 -> lA mean-half rows 2c, 2c+1
            const char* rb = smem + RAW_OFF(c & 1);
            int orow = tid >> 7;
            int cp = tid & 127;
            f32x2 s = {0.f, 0.f};
            #pragma unroll
            for (int j = 0; j < 10; ++j)
                s += *(const f32x2*)(rb + (orow * 10 + j) * 1024 + cp * 8);
            uint32_t pk = (uint32_t)f2bf(s[0] * 0.1f) | ((uint32_t)f2bf(s[1] * 0.1f) << 16);
            storeA4(lA, 2 * c + orow, 256 + cp * 2, pk);
        }
        __syncthreads();   // implicit vmcnt(0): stage(c+1) landed; raw[c&1] reusable
    }

    // ---- layer 1: lA[32][512] @ W1t^T -> relu -> bf16 lNH[32][256] (overlay)
    {
        f32x4 acc[2][4] = {};
        const u16* bp[4];
        #pragma unroll
        for (int nn = 0; nn < 4; ++nn)
            bp[nn] = W1t + (size_t)(w * 64 + nn * 16 + an) * 512 + ak;
        for (int kt = 0; kt < 8; ++kt) {
            const int kbase = kt * 64;
            s16x8 bF[2][4];
            #pragma unroll
            for (int ks = 0; ks < 2; ++ks)
                #pragma unroll
                for (int nn = 0; nn < 4; ++nn)
                    bF[ks][nn] = *(const s16x8*)(bp[nn] + kbase + ks * 32);
            #pragma unroll
            for (int ks = 0; ks < 2; ++ks) {
                s16x8 aF[2];
                #pragma unroll
                for (int m = 0; m < 2; ++m)
                    aF[m] = readA8(lA, m * 16 + an, kbase + ks * 32 + ak);
                #pragma unroll
                for (int m = 0; m < 2; ++m)
                    #pragma unroll
                    for (int nn = 0; nn < 4; ++nn)
                        acc[m][nn] = __builtin_amdgcn_mfma_f32_16x16x32_bf16(aF[m], bF[ks][nn], acc[m][nn], 0, 0, 0);
            }
        }
        // lNH overlays dead raw region (disjoint from lA) -> no barrier needed
        // C/D layout: col=lane&15, row=(lane>>4)*4+j [m89-verified]
        const int r0 = (lane >> 4) * 4;
        const int c0 = w * 64 + an;
        #pragma unroll
        for (int m = 0; m < 2; ++m)
            #pragma unroll
            for (int nn = 0; nn < 4; ++nn)
                #pragma unroll
                for (int j = 0; j < 4; ++j)
                    storeNH1(lNH, m * 16 + r0 + j, c0 + nn * 16, f2bf(fmaxf(acc[m][nn][j], 0.f)));
    }
    __syncthreads();   // lNH complete

    // ---- phase 2: lA2[16][512] = [ nh0 | mean10(nh1) ], rows 2-15 zero
    #pragma unroll
    for (int p = 0; p < 4; ++p) {
        int task = p * 256 + tid;                    // 16 rows x 64 quads
        int r = task >> 6;
        int c4 = (task & 63) * 4;
        u16x4 sb = {0, 0, 0, 0}, mb = {0, 0, 0, 0};
        if (r < 2) {
            sb = readNH4(lNH, 20 + r, c4);
            float a[4] = {0.f, 0.f, 0.f, 0.f};
            #pragma unroll
            for (int j = 0; j < 10; ++j) {
                u16x4 v = readNH4(lNH, 10 * r + j, c4);
                #pragma unroll
                for (int i = 0; i < 4; ++i) a[i] += bf2f(v[i]);
            }
            #pragma unroll
            for (int i = 0; i < 4; ++i) mb[i] = f2bf(a[i] * 0.1f);
        }
        storeA(lA2, r, c4, sb);
        storeA(lA2, r, 256 + c4, mb);
    }
    __syncthreads();

    // ---- layer 2: lA2[16][512] @ W2t^T -> f32 out rows 2b, 2b+1
    {
        f32x4 acc[4] = {};
        const u16* bp[4];
        #pragma unroll
        for (int nn = 0; nn < 4; ++nn)
            bp[nn] = W2t + (size_t)(w * 64 + nn * 16 + an) * 512 + ak;
        for (int kt = 0; kt < 8; ++kt) {
            const int kbase = kt * 64;
            s16x8 bF[2][4];
            #pragma unroll
            for (int ks = 0; ks < 2; ++ks)
                #pragma unroll
                for (int nn = 0; nn < 4; ++nn)
                    bF[ks][nn] = *(const s16x8*)(bp[nn] + kbase + ks * 32);
            #pragma unroll
            for (int ks = 0; ks < 2; ++ks) {
                s16x8 aF = readA8(lA2, an, kbase + ks * 32 + ak);
                #pragma unroll
                for (int nn = 0; nn < 4; ++nn)
                    acc[nn] = __builtin_amdgcn_mfma_f32_16x16x32_bf16(aF, bF[ks][nn], acc[nn], 0, 0, 0);
            }
        }
        const int r0 = (lane >> 4) * 4;
        const int c0 = w * 64 + an;
        #pragma unroll
        for (int nn = 0; nn < 4; ++nn)
            #pragma unroll
            for (int j = 0; j < 4; ++j) {
                int r = r0 + j;
                if (r < 2)
                    out[(size_t)(2 * b + r) * 256 + c0 + nn * 16] = acc[nn][j];
            }
    }
}

extern "C" void kernel_launch(void* const* d_in, const int* in_sizes, int n_in,
                              void* d_out, int out_size, void* d_ws, size_t ws_size,
                              hipStream_t stream) {
    const float* h0  = (const float*)d_in[0];
    const float* h1  = (const float*)d_in[1];
    const float* h2  = (const float*)d_in[2];
    const float* w1s = (const float*)d_in[3];
    const float* w1n = (const float*)d_in[4];
    const float* w2s = (const float*)d_in[5];
    const float* w2n = (const float*)d_in[6];

    char* ws = (char*)d_ws;
    u16* W1t = (u16*)ws; ws += (size_t)256 * 512 * 2;
    u16* W2t = (u16*)ws; ws += (size_t)256 * 512 * 2;
    (void)ws_size; (void)in_sizes; (void)n_in; (void)out_size;

    (void)hipFuncSetAttribute((const void*)sage_fused,
                              hipFuncAttributeMaxDynamicSharedMemorySize, K1_LDS);

    conv_w2t<<<64, 256, 0, stream>>>(w1s, w1n, w2s, w2n, W1t, W2t);

    // fused two-layer SAGE: 5000 blocks x 2 output rows, exact cones
    sage_fused<<<5000, 256, K1_LDS, stream>>>(h0, h1, h2, W1t, W2t, (float*)d_out);
}